// Round 7
// baseline (386.299 us; speedup 1.0000x reference)
//
#include <hip/hip_runtime.h>
#include <math.h>

#define BB 16384
#define DD 1024
#define RR 64
#define EE 4
#define ER 256   // EE*RR
#define LL 3

#define LDM 72   // mix-phase Tt stride

typedef __bf16 bf16x8 __attribute__((ext_vector_type(8)));
typedef float f32x4 __attribute__((ext_vector_type(4)));
typedef unsigned short us;

static __device__ inline us f2b(float f) {   // RNE f32->bf16
    union { float f; unsigned u; } c; c.f = f;
    return (us)((c.u + 0x7FFF + ((c.u >> 16) & 1)) >> 16);
}
static __device__ inline float b2f(us v) {
    union { unsigned u; float f; } c; c.u = ((unsigned)v) << 16;
    return c.f;
}
static __device__ inline float fast_tanh(float x) {
    float t = __expf(2.f * x);               // inf/0 at extremes -> +-1 exactly
    return 1.f - 2.f / (t + 1.f);
}

// generic f32 -> bf16 (4 elems/thread)
__global__ __launch_bounds__(256) void convF2B(const float* __restrict__ s, us* __restrict__ d) {
    int f = (blockIdx.x * 256 + threadIdx.x) * 4;
    float4 v = *(const float4*)&s[f];
    *(ushort4*)&d[f] = make_ushort4(f2b(v.x), f2b(v.y), f2b(v.z), f2b(v.w));
}
// V [le][d][r] f32 -> Vt [le][r][d] bf16
__global__ __launch_bounds__(256) void convV(const float* __restrict__ V, us* __restrict__ Vt) {
    const int le = blockIdx.x;
    const int d0 = blockIdx.y * 64;
    __shared__ float t[64 * 65];
    const int tid = threadIdx.x;
    const float* Vb = V + (size_t)le * DD * RR;
    #pragma unroll
    for (int p = 0; p < 4; ++p) {
        int f = tid + p * 256; int dd = f >> 4; int c = (f & 15) * 4;
        float4 v = *(const float4*)&Vb[(size_t)(d0 + dd) * RR + c];
        t[dd * 65 + c + 0] = v.x; t[dd * 65 + c + 1] = v.y;
        t[dd * 65 + c + 2] = v.z; t[dd * 65 + c + 3] = v.w;
    }
    __syncthreads();
    int r = tid >> 2, dg = (tid & 3) * 16;
    us o[16];
    #pragma unroll
    for (int k = 0; k < 16; ++k) o[k] = f2b(t[(dg + k) * 65 + r]);
    us* dst = Vt + (size_t)le * RR * DD + (size_t)r * DD + d0 + dg;
    #pragma unroll
    for (int q = 0; q < 4; ++q) *(ushort4*)&dst[q * 4] = *(ushort4*)&o[q * 4];
}

// Whole layer fused; block = 64 b-rows, 512 thr (8 waves), grid 256 (1 block/CU).
// Wave = (h = wave>>2 in {0,1}: 32-b half, e = wave&3: expert).
// Phase 1 is LDS-FREE and BARRIER-FREE: MFMA A/B fragments load directly from global
// (Vt is pre-transposed [r][d]; x is row-major) -> L1/L2-served, register-renamed
// load/MFMA overlap, no syncthreads-forced vmcnt(0) drains. Gate logits ride along
// as 1 extra MFMA on waves 0-3 (gw rows broadcast-loaded from global).
// Then: tanh -> Tt (wave-private, no barrier) -> C-mix (self reads) -> barrier ->
// w = g*tanh -> wlds (16B-chunk XOR swizzle) -> barrier -> phase 2 (barrier-free):
// wave owns 64 d x 2 passes, A-frags direct from global U (L2-hot), B from wlds;
// epilogue via wave-private smf transpose -> 16 contiguous d per lane -> fully
// coalesced x0/xl reads + out/xb writes.
__global__ __launch_bounds__(512, 2) void layer_fused(const us* __restrict__ xs,
                                                      const us* __restrict__ Vt,
                                                      const us* __restrict__ Ce,
                                                      const us* __restrict__ gwb,
                                                      const us* __restrict__ x0b,
                                                      const us* __restrict__ Ub,
                                                      us* __restrict__ xbo,
                                                      const float* __restrict__ biasl,
                                                      float* __restrict__ out, int last) {
    const int row0 = blockIdx.x * 64;
    const int tid = threadIdx.x;
    const int lane = tid & 63, wave = tid >> 6;
    const int l15 = lane & 15, quad = lane >> 4;
    const int e = wave & 3, h = wave >> 2;
    const int e64 = e * 64;

    __shared__ __align__(16) us    wlds[64 * 256];   // 32 KB
    __shared__ __align__(16) float smf[8][1024];     // 32 KB
    __shared__ __align__(16) us    Tt[4][64 * LDM];  // 36.9 KB
    __shared__ float gates[256];                     // 1 KB   (total ~101 KB, 1 blk/CU)

    const bool gw4 = (wave < 4);

    // phase-1 fragment base pointers (per-lane)
    const us* vA = Vt + (size_t)(e64 + l15) * DD + quad * 8;              // + mt*16*DD + t*32
    const us* xB = xs + (size_t)(row0 + h * 32 + l15) * DD + quad * 8;    // + nt*16*DD + t*32
    const us* gA = gwb + (size_t)(l15 & 3) * DD + quad * 8;               // + t*32
    const us* xG = xs + (size_t)(row0 + (wave & 3) * 16 + l15) * DD + quad * 8;  // waves 0-3

    f32x4 acc[4][2] = {};
    f32x4 accg = {};

    #pragma unroll
    for (int t = 0; t < 32; ++t) {
        const int kk = t * 32;
        bf16x8 A[4], B[2];
        A[0] = *(const bf16x8*)&vA[kk];
        A[1] = *(const bf16x8*)&vA[16 * DD + kk];
        A[2] = *(const bf16x8*)&vA[32 * DD + kk];
        A[3] = *(const bf16x8*)&vA[48 * DD + kk];
        B[0] = *(const bf16x8*)&xB[kk];
        B[1] = *(const bf16x8*)&xB[16 * DD + kk];
        #pragma unroll
        for (int mt = 0; mt < 4; ++mt)
            #pragma unroll
            for (int nt = 0; nt < 2; ++nt)
                acc[mt][nt] = __builtin_amdgcn_mfma_f32_16x16x32_bf16(A[mt], B[nt], acc[mt][nt], 0, 0, 0);
        if (gw4) {   // gate logits: rows 0-3 = experts, cols = b (wave*16+l15)
            bf16x8 GA = *(const bf16x8*)&gA[kk];
            bf16x8 GB = *(const bf16x8*)&xG[kk];
            accg = __builtin_amdgcn_mfma_f32_16x16x32_bf16(GA, GB, accg, 0, 0, 0);
        }
    }

    // tanh -> Tt_e[b][r] bf16 (wave-private rows; self-read only -> no barrier)
    #pragma unroll
    for (int mt = 0; mt < 4; ++mt)
        #pragma unroll
        for (int nt = 0; nt < 2; ++nt) {
            int b = h * 32 + nt * 16 + l15;
            us o[4];
            #pragma unroll
            for (int i = 0; i < 4; ++i) o[i] = f2b(fast_tanh(acc[mt][nt][i]));
            *(ushort4*)&Tt[e][b * LDM + mt * 16 + quad * 4] = *(ushort4*)o;
        }
    if (gw4 && quad == 0) {   // accg rows 0-3 = logits e0..e3 for b = wave*16+l15
        float l0 = accg[0], l1 = accg[1], l2 = accg[2], l3 = accg[3];
        float m = fmaxf(fmaxf(l0, l1), fmaxf(l2, l3));
        float g0 = __expf(l0 - m), g1 = __expf(l1 - m);
        float g2 = __expf(l2 - m), g3 = __expf(l3 - m);
        float inv = 1.f / (g0 + g1 + g2 + g3);
        int b = wave * 16 + l15;
        gates[0 * 64 + b] = g0 * inv; gates[1 * 64 + b] = g1 * inv;
        gates[2 * 64 + b] = g2 * inv; gates[3 * 64 + b] = g3 * inv;
    }

    // t2 = tanh(C_e @ t1); C-frags direct from global bf16 (L2-hot); Tt reads are
    // this wave's own writes (compiler inserts lgkmcnt for the RAW dep).
    const us* Cb = Ce + (size_t)e * RR * RR;
    f32x4 acc2[4][2] = {};
    #pragma unroll
    for (int ks = 0; ks < 2; ++ks) {
        bf16x8 af2[4], bf2[2];
        #pragma unroll
        for (int mt = 0; mt < 4; ++mt)
            af2[mt] = *(const bf16x8*)&Cb[(size_t)(mt * 16 + l15) * RR + ks * 32 + quad * 8];
        #pragma unroll
        for (int nt = 0; nt < 2; ++nt)
            bf2[nt] = *(const bf16x8*)&Tt[e][(h * 32 + nt * 16 + l15) * LDM + ks * 32 + quad * 8];
        #pragma unroll
        for (int mt = 0; mt < 4; ++mt)
            #pragma unroll
            for (int nt = 0; nt < 2; ++nt)
                acc2[mt][nt] = __builtin_amdgcn_mfma_f32_16x16x32_bf16(af2[mt], bf2[nt], acc2[mt][nt], 0, 0, 0);
    }
    __syncthreads();               // gates visible to all waves

    // w = g * tanh(acc2) -> wlds[b][col] with 16B-chunk XOR swizzle: cc' = cc ^ (b&7)
    #pragma unroll
    for (int mt = 0; mt < 4; ++mt)
        #pragma unroll
        for (int nt = 0; nt < 2; ++nt) {
            int b = h * 32 + nt * 16 + l15;
            float g = gates[e64 + b];
            us o[4];
            #pragma unroll
            for (int i = 0; i < 4; ++i) o[i] = f2b(g * fast_tanh(acc2[mt][nt][i]));
            int col = e64 + mt * 16 + quad * 4;
            int cc = col >> 3, off = col & 7;
            *(ushort4*)&wlds[b * 256 + ((cc ^ (b & 7)) << 3) + off] = *(ushort4*)o;
        }
    __syncthreads();               // wlds ready; phase 2 is barrier-free

    // ---- phase 2: D[d][b] = U . w^T; wave owns 64 d per pass, all 64 b ----
    const int bl = lane >> 2, dc3 = lane & 3;
    #pragma unroll 1
    for (int p = 0; p < 2; ++p) {
        const int dw = p * 512 + wave * 64;
        f32x4 pac[4][4] = {};
        #pragma unroll
        for (int s = 0; s < 8; ++s) {
            int e2 = s >> 1, r0 = (s & 1) * 32;
            bf16x8 af[4], bfr[4];
            #pragma unroll
            for (int mt = 0; mt < 4; ++mt) {
                int d = dw + mt * 16 + l15;
                af[mt] = *(const bf16x8*)&Ub[((size_t)e2 * DD + d) * RR + r0 + quad * 8];
            }
            #pragma unroll
            for (int nt = 0; nt < 4; ++nt) {
                int b = nt * 16 + l15;
                int cc = e2 * 8 + (r0 >> 3) + quad;
                bfr[nt] = *(const bf16x8*)&wlds[b * 256 + ((cc ^ (b & 7)) << 3)];
            }
            #pragma unroll
            for (int mt = 0; mt < 4; ++mt)
                #pragma unroll
                for (int nt = 0; nt < 4; ++nt)
                    pac[mt][nt] = __builtin_amdgcn_mfma_f32_16x16x32_bf16(af[mt], bfr[nt], pac[mt][nt], 0, 0, 0);
        }
        // epilogue: bias for my 16 d (nt-invariant), then per-nt transpose + combine
        const int dg = dw + dc3 * 16;
        float bfv[16];
        *(float4*)&bfv[0]  = *(const float4*)&biasl[dg];
        *(float4*)&bfv[4]  = *(const float4*)&biasl[dg + 4];
        *(float4*)&bfv[8]  = *(const float4*)&biasl[dg + 8];
        *(float4*)&bfv[12] = *(const float4*)&biasl[dg + 12];
        float* sw = smf[wave];     // wave-private 4 KB
        #pragma unroll
        for (int nt = 0; nt < 4; ++nt) {
            #pragma unroll
            for (int mt = 0; mt < 4; ++mt) {
                int ch = (mt * 4 + quad) ^ (l15 & 7);
                *(f32x4*)&sw[l15 * 64 + ch * 4] = pac[mt][nt];
            }
            asm volatile("s_waitcnt lgkmcnt(0)" ::: "memory");
            __builtin_amdgcn_sched_barrier(0);
            const int brow = row0 + nt * 16 + bl;
            const size_t gb = (size_t)brow * DD + dg;
            uint xu[8], lu[8];
            *(uint4*)&xu[0] = *(const uint4*)&x0b[gb];
            *(uint4*)&xu[4] = *(const uint4*)&x0b[gb + 8];
            *(uint4*)&lu[0] = *(const uint4*)&xs[gb];
            *(uint4*)&lu[4] = *(const uint4*)&xs[gb + 8];
            float o[16];
            #pragma unroll
            for (int j = 0; j < 4; ++j) {
                int ch = (dc3 * 4 + j) ^ (bl & 7);
                float4 a = *(const float4*)&sw[bl * 64 + ch * 4];
                #pragma unroll
                for (int i = 0; i < 4; ++i) {
                    int k = j * 4 + i;
                    float av = (i == 0) ? a.x : (i == 1) ? a.y : (i == 2) ? a.z : a.w;
                    uint uu = xu[k >> 1], ll = lu[k >> 1];
                    float xv = b2f((k & 1) ? (us)(uu >> 16) : (us)(uu & 0xffff));
                    float xl = b2f((k & 1) ? (us)(ll >> 16) : (us)(ll & 0xffff));
                    o[k] = xv * (av + bfv[k]) + xl;
                }
            }
            if (last) {
                *(float4*)&out[gb]      = *(float4*)&o[0];
                *(float4*)&out[gb + 4]  = *(float4*)&o[4];
                *(float4*)&out[gb + 8]  = *(float4*)&o[8];
                *(float4*)&out[gb + 12] = *(float4*)&o[12];
            } else {
                us ob[16];
                #pragma unroll
                for (int k = 0; k < 16; ++k) ob[k] = f2b(o[k]);
                *(uint4*)&xbo[gb]     = *(uint4*)&ob[0];
                *(uint4*)&xbo[gb + 8] = *(uint4*)&ob[8];
            }
            asm volatile("s_waitcnt lgkmcnt(0)" ::: "memory");   // smf reads done before next nt writes
            __builtin_amdgcn_sched_barrier(0);
        }
    }
}

extern "C" void kernel_launch(void* const* d_in, const int* in_sizes, int n_in,
                              void* d_out, int out_size, void* d_ws, size_t ws_size,
                              hipStream_t stream) {
    const float* inputs = (const float*)d_in[0];
    const float* U      = (const float*)d_in[1];
    const float* V      = (const float*)d_in[2];
    const float* C      = (const float*)d_in[3];
    const float* gw     = (const float*)d_in[4];
    const float* bias   = (const float*)d_in[5];
    float* out = (float*)d_out;

    // ws: xb0 33.55 | xb 33.55 | gwb 8KB | Vt 1.57 | Ub 1.57 | Cb 0.10  = ~70.3 MB
    us* xb0 = (us*)d_ws;                         // bf16(inputs), const across layers
    us* xb  = xb0 + (size_t)BB * DD;             // residual stream
    us* gwb = xb + (size_t)BB * DD;
    us* Vt  = gwb + (size_t)EE * DD;
    us* Ub  = Vt + (size_t)LL * EE * RR * DD;
    us* Cb  = Ub + (size_t)LL * EE * DD * RR;

    convF2B<<<dim3(BB * DD / 1024), 256, 0, stream>>>(inputs, xb0);
    convF2B<<<dim3(LL * EE * DD * RR / 1024), 256, 0, stream>>>(U, Ub);
    convF2B<<<dim3(LL * EE * RR * RR / 1024), 256, 0, stream>>>(C, Cb);
    convF2B<<<dim3(EE * DD / 1024), 256, 0, stream>>>(gw, gwb);
    convV<<<dim3(LL * EE, DD / 64), 256, 0, stream>>>(V, Vt);

    for (int i = 0; i < LL; ++i) {
        const us* xs = (i == 0) ? xb0 : xb;
        layer_fused<<<dim3(BB / 64), 512, 0, stream>>>(
            xs, Vt + (size_t)i * EE * RR * DD, Cb + (size_t)i * EE * RR * RR, gwb,
            xb0, Ub + (size_t)i * EE * DD * RR, xb, bias + (size_t)i * DD,
            out, i == LL - 1);
    }
}

// Round 8
// 276.460 us; speedup vs baseline: 1.3973x; 1.3973x over previous
//
#include <hip/hip_runtime.h>
#include <math.h>

#define BB 16384
#define DD 1024
#define RR 64
#define EE 4
#define ER 256   // EE*RR
#define LL 3

#define LDM 72   // mix-phase Tt stride

typedef __bf16 bf16x8 __attribute__((ext_vector_type(8)));
typedef float f32x4 __attribute__((ext_vector_type(4)));
typedef unsigned short us;

static __device__ inline us f2b(float f) {   // RNE f32->bf16
    union { float f; unsigned u; } c; c.f = f;
    return (us)((c.u + 0x7FFF + ((c.u >> 16) & 1)) >> 16);
}
static __device__ inline float b2f(us v) {
    union { unsigned u; float f; } c; c.u = ((unsigned)v) << 16;
    return c.f;
}
static __device__ inline float fast_tanh(float x) {
    float t = __expf(2.f * x);               // inf/0 at extremes -> +-1 exactly
    return 1.f - 2.f / (t + 1.f);
}
// async global->LDS, 16B/lane; dst is wave-uniform base, HW writes lane i at base+i*16
static __device__ __forceinline__ void ld_lds16(const us* g, us* l) {
    __builtin_amdgcn_global_load_lds((const __attribute__((address_space(1))) void*)g,
                                     (__attribute__((address_space(3))) void*)l, 16, 0, 0);
}

// generic f32 -> bf16 (4 elems/thread)
__global__ __launch_bounds__(256) void convF2B(const float* __restrict__ s, us* __restrict__ d) {
    int f = (blockIdx.x * 256 + threadIdx.x) * 4;
    float4 v = *(const float4*)&s[f];
    *(ushort4*)&d[f] = make_ushort4(f2b(v.x), f2b(v.y), f2b(v.z), f2b(v.w));
}
// V [le][d][r] f32 -> Vt [le][r][d] bf16
__global__ __launch_bounds__(256) void convV(const float* __restrict__ V, us* __restrict__ Vt) {
    const int le = blockIdx.x;
    const int d0 = blockIdx.y * 64;
    __shared__ float t[64 * 65];
    const int tid = threadIdx.x;
    const float* Vb = V + (size_t)le * DD * RR;
    #pragma unroll
    for (int p = 0; p < 4; ++p) {
        int f = tid + p * 256; int dd = f >> 4; int c = (f & 15) * 4;
        float4 v = *(const float4*)&Vb[(size_t)(d0 + dd) * RR + c];
        t[dd * 65 + c + 0] = v.x; t[dd * 65 + c + 1] = v.y;
        t[dd * 65 + c + 2] = v.z; t[dd * 65 + c + 3] = v.w;
    }
    __syncthreads();
    int r = tid >> 2, dg = (tid & 3) * 16;
    us o[16];
    #pragma unroll
    for (int k = 0; k < 16; ++k) o[k] = f2b(t[(dg + k) * 65 + r]);
    us* dst = Vt + (size_t)le * RR * DD + (size_t)r * DD + d0 + dg;
    #pragma unroll
    for (int q = 0; q < 4; ++q) *(ushort4*)&dst[q * 4] = *(ushort4*)&o[q * 4];
}

// Whole layer fused; block = 64 b-rows, 512 thr (8 waves), grid 256 (1 block/CU).
// Wave = (h = wave>>2: 32-b half, e = wave&3: expert).
// Phase 1: D_e[r][b] over K=1024, BK=64 tiles (16 iters), 3 LDS bufs, 2-deep prefetch,
// ONE barrier/iter, uniform 5 DMA loads/thread/tile -> single vmcnt(5) for all waves.
// Granule (16B) layout: row-chunk c stored at slot c^(row&7) -> coalesced 128B-per-row
// DMA sources AND <=2-way bank aliasing on ds_read_b128 fragment reads.
// Gate logits ride along as 2 MFMA/iter on waves 0-3. tanh -> Tt -> C-mix ->
// w=g*tanh -> wlds (16B-chunk XOR swizzle; w never touches HBM) -> phase 2
// (barrier-free): wave owns 64 d x 2 passes, U-frags from global (L2-hot) with
// ping-pong prefetch, B from wlds; epilogue hoists all x0/xl loads, then wave-private
// smf transpose -> 16 contiguous d per lane -> fully coalesced reads + writes.
__global__ __launch_bounds__(512, 2) void layer_fused(const us* __restrict__ xs,
                                                      const us* __restrict__ Vt,
                                                      const us* __restrict__ Ce,
                                                      const us* __restrict__ gwb,
                                                      const us* __restrict__ x0b,
                                                      const us* __restrict__ Ub,
                                                      us* __restrict__ xbo,
                                                      const float* __restrict__ biasl,
                                                      float* __restrict__ out, int last) {
    const int row0 = blockIdx.x * 64;
    const int tid = threadIdx.x;
    const int lane = tid & 63, wave = tid >> 6;
    const int l15 = lane & 15, quad = lane >> 4;
    const int e = wave & 3, h = wave >> 2;
    const int e64 = e * 64;

    __shared__ __align__(16) union {
        struct { us buf[3][20480]; us gw[4096]; float gates[256]; } s;  // 129 KB
        us Tt[4][64 * LDM];                                             // 36.9 KB (aliases buf)
        struct { us wlds[64 * 256]; float smf[8][1024]; } p2;           // 64 KB (aliases buf)
    } u;

    const bool gw4 = (wave < 4);
    const int r8   = lane >> 3;                 // 0..7
    const int cA8  = (lane & 7) ^ r8;           // DMA source chunk (8-elem granules)
    const int l7   = l15 & 7;                   // read-side XOR key (row&7)

    // gw once: granule = kc*4 + gwrow; thread covers kc = wave*16 + (lane>>2), row = lane&3
    ld_lds16(gwb + (size_t)(lane & 3) * DD + (wave * 16 + (lane >> 2)) * 8, &u.s.gw[wave * 512]);

    auto STAGE = [&](int bi, int k0) {
        us* bb = u.s.buf[bi];
        #pragma unroll
        for (int j = 0; j < 4; ++j) {           // Av: rows wave*32 + j*8 + r8, full 128B/row
            int row = wave * 32 + j * 8 + r8;
            ld_lds16(Vt + (size_t)row * DD + k0 + cA8 * 8, &bb[(wave * 256 + j * 64) * 8]);
        }
        {                                       // Bx: rows wave*8 + r8 (64 rows total)
            int row = wave * 8 + r8;
            ld_lds16(xs + (size_t)(row0 + row) * DD + k0 + cA8 * 8, &bb[16384 + wave * 512]);
        }
    };

    f32x4 acc[4][2] = {};
    f32x4 accg = {};
    STAGE(0, 0); STAGE(1, 64);

    int cur = 0;
    for (int t = 0; t < 16; ++t) {
        if (t < 15) asm volatile("s_waitcnt vmcnt(5)" ::: "memory");  // tile t complete
        else        asm volatile("s_waitcnt vmcnt(0)" ::: "memory");
        __builtin_amdgcn_s_barrier();           // tile t ready everywhere; buf(t-1) reads done
        if (t < 14) {                           // stage tile t+2 into buf freed at iter t-1
            int st = cur + 2; if (st >= 3) st -= 3;
            STAGE(st, (t + 2) * 64);
        }
        __builtin_amdgcn_sched_barrier(0);
        const us* bb = u.s.buf[cur];
        #pragma unroll
        for (int ks = 0; ks < 2; ++ks) {
            const int sl = ((ks * 4 + quad) ^ l7) * 8;
            bf16x8 af[4], bfr[2];
            #pragma unroll
            for (int mt = 0; mt < 4; ++mt)
                af[mt] = *(const bf16x8*)&bb[(e64 + mt * 16 + l15) * 64 + sl];
            #pragma unroll
            for (int nt = 0; nt < 2; ++nt)
                bfr[nt] = *(const bf16x8*)&bb[16384 + (h * 32 + nt * 16 + l15) * 64 + sl];
            #pragma unroll
            for (int mt = 0; mt < 4; ++mt)
                #pragma unroll
                for (int nt = 0; nt < 2; ++nt)
                    acc[mt][nt] = __builtin_amdgcn_mfma_f32_16x16x32_bf16(af[mt], bfr[nt], acc[mt][nt], 0, 0, 0);
            if (gw4) {   // gate logits: rows 0-3 = experts, col b = wave*16+l15
                bf16x8 bfrg = *(const bf16x8*)&bb[16384 + (wave * 16 + l15) * 64 + sl];
                bf16x8 afg  = *(const bf16x8*)&u.s.gw[((t * 8 + ks * 4 + quad) * 4 + (l15 & 3)) * 8];
                accg = __builtin_amdgcn_mfma_f32_16x16x32_bf16(afg, bfrg, accg, 0, 0, 0);
            }
        }
        cur = (cur == 2) ? 0 : cur + 1;
    }
    __builtin_amdgcn_s_barrier();               // all buf reads done before Tt alias writes
    __builtin_amdgcn_sched_barrier(0);

    // tanh -> Tt_e[b][r] bf16 (wave writes its own (e,h) region)
    #pragma unroll
    for (int mt = 0; mt < 4; ++mt)
        #pragma unroll
        for (int nt = 0; nt < 2; ++nt) {
            int b = h * 32 + nt * 16 + l15;
            us o[4];
            #pragma unroll
            for (int i = 0; i < 4; ++i) o[i] = f2b(fast_tanh(acc[mt][nt][i]));
            *(ushort4*)&u.Tt[e][b * LDM + mt * 16 + quad * 4] = *(ushort4*)o;
        }
    if (gw4 && quad == 0) {   // accg rows 0-3 = logits e0..e3 for b = wave*16+l15
        float l0 = accg[0], l1 = accg[1], l2 = accg[2], l3 = accg[3];
        float m = fmaxf(fmaxf(l0, l1), fmaxf(l2, l3));
        float g0 = __expf(l0 - m), g1 = __expf(l1 - m);
        float g2 = __expf(l2 - m), g3 = __expf(l3 - m);
        float inv = 1.f / (g0 + g1 + g2 + g3);
        int b = wave * 16 + l15;
        u.s.gates[0 * 64 + b] = g0 * inv; u.s.gates[1 * 64 + b] = g1 * inv;
        u.s.gates[2 * 64 + b] = g2 * inv; u.s.gates[3 * 64 + b] = g3 * inv;
    }
    __syncthreads();

    // t2 = tanh(C_e @ t1); C-frags direct from global bf16 (L2-hot)
    const us* Cb = Ce + (size_t)e * RR * RR;
    f32x4 acc2[4][2] = {};
    #pragma unroll
    for (int ks = 0; ks < 2; ++ks) {
        bf16x8 af2[4], bf2[2];
        #pragma unroll
        for (int mt = 0; mt < 4; ++mt)
            af2[mt] = *(const bf16x8*)&Cb[(size_t)(mt * 16 + l15) * RR + ks * 32 + quad * 8];
        #pragma unroll
        for (int nt = 0; nt < 2; ++nt)
            bf2[nt] = *(const bf16x8*)&u.Tt[e][(h * 32 + nt * 16 + l15) * LDM + ks * 32 + quad * 8];
        #pragma unroll
        for (int mt = 0; mt < 4; ++mt)
            #pragma unroll
            for (int nt = 0; nt < 2; ++nt)
                acc2[mt][nt] = __builtin_amdgcn_mfma_f32_16x16x32_bf16(af2[mt], bf2[nt], acc2[mt][nt], 0, 0, 0);
    }
    __syncthreads();               // ALL Tt reads done before wlds (aliases Tt) writes

    // w = g * tanh(acc2) -> wlds[b][col] with 16B-chunk XOR swizzle: cc' = cc ^ (b&7)
    #pragma unroll
    for (int mt = 0; mt < 4; ++mt)
        #pragma unroll
        for (int nt = 0; nt < 2; ++nt) {
            int b = h * 32 + nt * 16 + l15;
            float g = u.s.gates[e64 + b];
            us o[4];
            #pragma unroll
            for (int i = 0; i < 4; ++i) o[i] = f2b(g * fast_tanh(acc2[mt][nt][i]));
            int col = e64 + mt * 16 + quad * 4;
            int cc = col >> 3, off = col & 7;
            *(ushort4*)&u.p2.wlds[b * 256 + ((cc ^ (b & 7)) << 3) + off] = *(ushort4*)o;
        }
    __syncthreads();               // wlds ready; phase 2 is barrier-free

    // ---- phase 2: D[d][b] = U . w^T; wave owns 64 d per pass, all 64 b ----
    const int bl = lane >> 2, dc3 = lane & 3;
    #pragma unroll 1
    for (int p = 0; p < 2; ++p) {
        const int dw = p * 512 + wave * 64;
        f32x4 pac[4][4] = {};
        bf16x8 a0[4], a1[4];
        #define LOADU(dst, S) { const int e2 = (S) >> 1, r0q = ((S) & 1) * 32;            \
            _Pragma("unroll")                                                              \
            for (int mt = 0; mt < 4; ++mt) {                                               \
                int d = dw + mt * 16 + l15;                                                \
                dst[mt] = *(const bf16x8*)&Ub[((size_t)e2 * DD + d) * RR + r0q + quad * 8];\
            } }
        #define LOADW(dst, S) { const int e2 = (S) >> 1, r0q = ((S) & 1) * 32;            \
            _Pragma("unroll")                                                              \
            for (int nt = 0; nt < 4; ++nt) {                                               \
                int b = nt * 16 + l15;                                                     \
                int cc = e2 * 8 + (r0q >> 3) + quad;                                       \
                dst[nt] = *(const bf16x8*)&u.p2.wlds[b * 256 + ((cc ^ (b & 7)) << 3)];     \
            } }
        #define MM(A, W) { _Pragma("unroll")                                               \
            for (int mt = 0; mt < 4; ++mt) { _Pragma("unroll")                             \
                for (int nt = 0; nt < 4; ++nt)                                             \
                    pac[mt][nt] = __builtin_amdgcn_mfma_f32_16x16x32_bf16(A[mt], W[nt], pac[mt][nt], 0, 0, 0); } }
        LOADU(a0, 0);
        #pragma unroll
        for (int sp = 0; sp < 4; ++sp) {
            bf16x8 w0[4], w1[4];
            LOADU(a1, 2 * sp + 1);
            LOADW(w0, 2 * sp);
            MM(a0, w0);
            if (sp < 3) LOADU(a0, 2 * sp + 2);
            LOADW(w1, 2 * sp + 1);
            MM(a1, w1);
        }
        #undef LOADU
        #undef LOADW
        #undef MM

        // epilogue: hoist ALL x0/xs loads for this pass (4 nt), then bias, transpose, store
        const int dg = dw + dc3 * 16;
        uint4 X[4][2], L[4][2];
        #pragma unroll
        for (int nt = 0; nt < 4; ++nt) {
            const size_t gb = (size_t)(row0 + nt * 16 + bl) * DD + dg;
            X[nt][0] = *(const uint4*)&x0b[gb];     X[nt][1] = *(const uint4*)&x0b[gb + 8];
            L[nt][0] = *(const uint4*)&xs[gb];      L[nt][1] = *(const uint4*)&xs[gb + 8];
        }
        float bfv[16];
        *(float4*)&bfv[0]  = *(const float4*)&biasl[dg];
        *(float4*)&bfv[4]  = *(const float4*)&biasl[dg + 4];
        *(float4*)&bfv[8]  = *(const float4*)&biasl[dg + 8];
        *(float4*)&bfv[12] = *(const float4*)&biasl[dg + 12];
        float* sw = u.p2.smf[wave];   // wave-private 4 KB; per-wave DS ops are in-order
        #pragma unroll
        for (int nt = 0; nt < 4; ++nt) {
            #pragma unroll
            for (int mt = 0; mt < 4; ++mt) {
                int ch = (mt * 4 + quad) ^ (l15 & 7);
                *(f32x4*)&sw[l15 * 64 + ch * 4] = pac[mt][nt];
            }
            asm volatile("s_waitcnt lgkmcnt(0)" ::: "memory");
            __builtin_amdgcn_sched_barrier(0);
            const size_t gb = (size_t)(row0 + nt * 16 + bl) * DD + dg;
            uint xu[8], lu[8];
            *(uint4*)&xu[0] = X[nt][0]; *(uint4*)&xu[4] = X[nt][1];
            *(uint4*)&lu[0] = L[nt][0]; *(uint4*)&lu[4] = L[nt][1];
            float o[16];
            #pragma unroll
            for (int j = 0; j < 4; ++j) {
                int ch = (dc3 * 4 + j) ^ (bl & 7);
                float4 a = *(const float4*)&sw[bl * 64 + ch * 4];
                #pragma unroll
                for (int i = 0; i < 4; ++i) {
                    int k = j * 4 + i;
                    float av = (i == 0) ? a.x : (i == 1) ? a.y : (i == 2) ? a.z : a.w;
                    uint uu = xu[k >> 1], ll = lu[k >> 1];
                    float xv = b2f((k & 1) ? (us)(uu >> 16) : (us)(uu & 0xffff));
                    float xl = b2f((k & 1) ? (us)(ll >> 16) : (us)(ll & 0xffff));
                    o[k] = xv * (av + bfv[k]) + xl;
                }
            }
            if (last) {
                *(float4*)&out[gb]      = *(float4*)&o[0];
                *(float4*)&out[gb + 4]  = *(float4*)&o[4];
                *(float4*)&out[gb + 8]  = *(float4*)&o[8];
                *(float4*)&out[gb + 12] = *(float4*)&o[12];
            } else {
                us ob[16];
                #pragma unroll
                for (int k = 0; k < 16; ++k) ob[k] = f2b(o[k]);
                *(uint4*)&xbo[gb]     = *(uint4*)&ob[0];
                *(uint4*)&xbo[gb + 8] = *(uint4*)&ob[8];
            }
        }
    }
}

extern "C" void kernel_launch(void* const* d_in, const int* in_sizes, int n_in,
                              void* d_out, int out_size, void* d_ws, size_t ws_size,
                              hipStream_t stream) {
    const float* inputs = (const float*)d_in[0];
    const float* U      = (const float*)d_in[1];
    const float* V      = (const float*)d_in[2];
    const float* C      = (const float*)d_in[3];
    const float* gw     = (const float*)d_in[4];
    const float* bias   = (const float*)d_in[5];
    float* out = (float*)d_out;

    // ws: xb0 33.55 | xb 33.55 | gwb 8KB | Vt 1.57 | Ub 1.57 | Cb 0.10  = ~70.3 MB
    us* xb0 = (us*)d_ws;                         // bf16(inputs), const across layers
    us* xb  = xb0 + (size_t)BB * DD;             // residual stream
    us* gwb = xb + (size_t)BB * DD;
    us* Vt  = gwb + (size_t)EE * DD;
    us* Ub  = Vt + (size_t)LL * EE * RR * DD;
    us* Cb  = Ub + (size_t)LL * EE * DD * RR;

    convF2B<<<dim3(BB * DD / 1024), 256, 0, stream>>>(inputs, xb0);
    convF2B<<<dim3(LL * EE * DD * RR / 1024), 256, 0, stream>>>(U, Ub);
    convF2B<<<dim3(LL * EE * RR * RR / 1024), 256, 0, stream>>>(C, Cb);
    convF2B<<<dim3(EE * DD / 1024), 256, 0, stream>>>(gw, gwb);
    convV<<<dim3(LL * EE, DD / 64), 256, 0, stream>>>(V, Vt);

    for (int i = 0; i < LL; ++i) {
        const us* xs = (i == 0) ? xb0 : xb;
        layer_fused<<<dim3(BB / 64), 512, 0, stream>>>(
            xs, Vt + (size_t)i * EE * RR * DD, Cb + (size_t)i * EE * RR * RR, gwb,
            xb0, Ub + (size_t)i * EE * DD * RR, xb, bias + (size_t)i * DD,
            out, i == LL - 1);
    }
}

// Round 9
// 262.326 us; speedup vs baseline: 1.4726x; 1.0539x over previous
//
#include <hip/hip_runtime.h>
#include <math.h>

#define BB 16384
#define DD 1024
#define RR 64
#define EE 4
#define ER 256   // EE*RR
#define LL 3

#define LDM 72   // mix-phase Tt stride

typedef __bf16 bf16x8 __attribute__((ext_vector_type(8)));
typedef float f32x4 __attribute__((ext_vector_type(4)));
typedef unsigned short us;

static __device__ inline us f2b(float f) {   // RNE f32->bf16
    union { float f; unsigned u; } c; c.f = f;
    return (us)((c.u + 0x7FFF + ((c.u >> 16) & 1)) >> 16);
}
static __device__ inline float b2f(us v) {
    union { unsigned u; float f; } c; c.u = ((unsigned)v) << 16;
    return c.f;
}
static __device__ inline float fast_tanh(float x) {
    float t = __expf(2.f * x);               // inf/0 at extremes -> +-1 exactly
    return 1.f - 2.f / (t + 1.f);
}
// async global->LDS, 16B/lane; dst is wave-uniform base, HW writes lane i at base+i*16
static __device__ __forceinline__ void ld_lds16(const us* g, us* l) {
    __builtin_amdgcn_global_load_lds((const __attribute__((address_space(1))) void*)g,
                                     (__attribute__((address_space(3))) void*)l, 16, 0, 0);
}

// generic f32 -> bf16 (4 elems/thread) -- inputs and gw
__global__ __launch_bounds__(256) void convF2B(const float* __restrict__ s, us* __restrict__ d) {
    int f = (blockIdx.x * 256 + threadIdx.x) * 4;
    float4 v = *(const float4*)&s[f];
    *(ushort4*)&d[f] = make_ushort4(f2b(v.x), f2b(v.y), f2b(v.z), f2b(v.w));
}

// V [le][d][r] f32 -> PACKED Vp: per layer, granule(16B) idx = (kt*256 + row)*8 + slot,
// slot = ((d>>3)&7) ^ (row&7), kt = d>>6, row = e*64 + r. This is exactly the LDS image
// phase 1 used in round 8, so DMA is a contiguous 1KB copy per instruction.
__global__ __launch_bounds__(256) void convV(const float* __restrict__ V, us* __restrict__ Vt) {
    const int le = blockIdx.x;
    const int d0 = blockIdx.y * 64;                  // kt = blockIdx.y
    __shared__ float t[64 * 65];
    const int tid = threadIdx.x;
    const float* Vb = V + (size_t)le * DD * RR;
    #pragma unroll
    for (int p = 0; p < 4; ++p) {
        int f = tid + p * 256; int dd = f >> 4; int c = (f & 15) * 4;
        float4 v = *(const float4*)&Vb[(size_t)(d0 + dd) * RR + c];
        t[dd * 65 + c + 0] = v.x; t[dd * 65 + c + 1] = v.y;
        t[dd * 65 + c + 2] = v.z; t[dd * 65 + c + 3] = v.w;
    }
    __syncthreads();
    int r = tid >> 2, dg = (tid & 3) * 16;
    us o[16];
    #pragma unroll
    for (int k = 0; k < 16; ++k) o[k] = f2b(t[(dg + k) * 65 + r]);
    const int l = le >> 2, eV = le & 3;
    const int row = eV * 64 + r, kt = blockIdx.y;
    us* dstL = Vt + (size_t)l * (EE * RR * DD);
    #pragma unroll
    for (int q = 0; q < 4; ++q) {
        int dd = dg + q * 4;
        int slot = ((dd >> 3) ^ row) & 7;
        *(ushort4*)&dstL[(((size_t)kt * 256 + row) * 8 + slot) * 8 + (dd & 7)] = *(ushort4*)&o[q * 4];
    }
}

// U [l][e][d][r] f32 -> PACKED Up: granule idx = ((e*2+rh)*64 + dblk)*64 + lane,
// lane = quad*16 + (d&15), holding elems (d, r = rh*32+quad*8+i). MFMA A-frag loads
// become base + lane*16B (fully coalesced).
__global__ __launch_bounds__(256) void convU(const float* __restrict__ U, us* __restrict__ Up) {
    int gid = blockIdx.x * 256 + threadIdx.x;        // 98304 threads
    int rb = (gid & 7) * 8;
    int d  = (gid >> 3) & 1023;
    int e  = (gid >> 13) & 3;
    int l  = gid >> 15;
    const float* s = U + (((size_t)(l * 4 + e) * 1024 + d) * 64 + rb);
    float4 v0 = *(const float4*)&s[0], v1 = *(const float4*)&s[4];
    us o[8] = { f2b(v0.x), f2b(v0.y), f2b(v0.z), f2b(v0.w),
                f2b(v1.x), f2b(v1.y), f2b(v1.z), f2b(v1.w) };
    int rh = rb >> 5, quad = (rb & 31) >> 3;
    int lane = quad * 16 + (d & 15), dblk = d >> 4;
    us* dst = Up + (size_t)l * (EE * DD * RR) + (size_t)(((e * 2 + rh) * 64 + dblk) * 64 + lane) * 8;
    *(ushort4*)&dst[0] = *(ushort4*)&o[0];
    *(ushort4*)&dst[4] = *(ushort4*)&o[4];
}

// C [l][e][r'][s] f32 -> PACKED Cp: granule idx = ((e*2+ks)*4 + mt)*64 + lane,
// lane = quad*16 + (r'&15), holding elems (r', s = ks*32+quad*8+i).
__global__ __launch_bounds__(256) void convC(const float* __restrict__ C, us* __restrict__ Cp) {
    int gid = blockIdx.x * 256 + threadIdx.x;        // 6144 threads
    int sb = (gid & 7) * 8;
    int r  = (gid >> 3) & 63;
    int e  = (gid >> 9) & 3;
    int l  = gid >> 11;
    const float* s = C + (((size_t)(l * 4 + e) * 64 + r) * 64 + sb);
    float4 v0 = *(const float4*)&s[0], v1 = *(const float4*)&s[4];
    us o[8] = { f2b(v0.x), f2b(v0.y), f2b(v0.z), f2b(v0.w),
                f2b(v1.x), f2b(v1.y), f2b(v1.z), f2b(v1.w) };
    int ks = sb >> 5, quad = (sb & 31) >> 3;
    int lane = quad * 16 + (r & 15), mt = r >> 4;
    us* dst = Cp + (size_t)l * (EE * RR * RR) + (size_t)(((e * 2 + ks) * 4 + mt) * 64 + lane) * 8;
    *(ushort4*)&dst[0] = *(ushort4*)&o[0];
    *(ushort4*)&dst[4] = *(ushort4*)&o[4];
}

// Whole layer fused; block = 64 b-rows, 512 thr (8 waves), grid 256 (1 block/CU).
// Wave = (h = wave>>2: 32-b half, e = wave&3: expert).
// Phase 1: BK=64 tiles (16 iters), 3 LDS bufs, 2-deep prefetch, ONE barrier/iter,
// uniform 5 DMA loads/thread/tile -> single vmcnt(5). Av DMA now reads CONTIGUOUS 1KB
// per instruction from packed Vp (LDS image identical to round 8). Gate logits ride
// along (2 MFMA/iter, waves 0-3). tanh -> Tt -> C-mix (packed Cp, coalesced) ->
// w=g*tanh -> wlds (16B-chunk XOR swizzle) -> phase 2 (barrier-free): U-frags from
// packed Up = base + lane*16B coalesced, ping-pong prefetch; epilogue hoists x0/xl
// loads, wave-private smf transpose -> 16 contiguous d per lane.
__global__ __launch_bounds__(512, 2) void layer_fused(const us* __restrict__ xs,
                                                      const us* __restrict__ Vp,
                                                      const us* __restrict__ Cp,
                                                      const us* __restrict__ gwb,
                                                      const us* __restrict__ x0b,
                                                      const us* __restrict__ Up,
                                                      us* __restrict__ xbo,
                                                      const float* __restrict__ biasl,
                                                      float* __restrict__ out, int last) {
    const int row0 = blockIdx.x * 64;
    const int tid = threadIdx.x;
    const int lane = tid & 63, wave = tid >> 6;
    const int l15 = lane & 15, quad = lane >> 4;
    const int e = wave & 3, h = wave >> 2;
    const int e64 = e * 64;

    __shared__ __align__(16) union {
        struct { us buf[3][20480]; us gw[4096]; float gates[256]; } s;  // 129 KB
        us Tt[4][64 * LDM];                                             // 36.9 KB (aliases buf)
        struct { us wlds[64 * 256]; float smf[8][1024]; } p2;           // 64 KB (aliases buf)
    } u;

    const bool gw4 = (wave < 4);
    const int r8   = lane >> 3;                 // 0..7
    const int cA8  = (lane & 7) ^ r8;           // x DMA source chunk
    const int l7   = l15 & 7;                   // read-side XOR key (row&7)

    // gw once: granule = kc*4 + gwrow; thread covers kc = wave*16 + (lane>>2), row = lane&3
    ld_lds16(gwb + (size_t)(lane & 3) * DD + (wave * 16 + (lane >> 2)) * 8, &u.s.gw[wave * 512]);

    auto STAGE = [&](int bi, int k0) {
        us* bb = u.s.buf[bi];
        const us* vsrc = Vp + (((size_t)(k0 >> 6) * 256 + wave * 32) * 8) * 8 + lane * 8;
        #pragma unroll
        for (int j = 0; j < 4; ++j)             // Av: contiguous 1KB per instruction
            ld_lds16(vsrc + j * 512, &bb[(wave * 256 + j * 64) * 8]);
        {                                       // Bx: rows wave*8 + r8 (64 rows total)
            int row = wave * 8 + r8;
            ld_lds16(xs + (size_t)(row0 + row) * DD + k0 + cA8 * 8, &bb[16384 + wave * 512]);
        }
    };

    f32x4 acc[4][2] = {};
    f32x4 accg = {};
    STAGE(0, 0); STAGE(1, 64);

    int cur = 0;
    for (int t = 0; t < 16; ++t) {
        if (t < 15) asm volatile("s_waitcnt vmcnt(5)" ::: "memory");  // tile t complete
        else        asm volatile("s_waitcnt vmcnt(0)" ::: "memory");
        __builtin_amdgcn_s_barrier();           // tile t ready everywhere; buf(t-1) reads done
        if (t < 14) {                           // stage tile t+2 into buf freed at iter t-1
            int st = cur + 2; if (st >= 3) st -= 3;
            STAGE(st, (t + 2) * 64);
        }
        __builtin_amdgcn_sched_barrier(0);
        const us* bb = u.s.buf[cur];
        #pragma unroll
        for (int ks = 0; ks < 2; ++ks) {
            const int sl = ((ks * 4 + quad) ^ l7) * 8;
            bf16x8 af[4], bfr[2];
            #pragma unroll
            for (int mt = 0; mt < 4; ++mt)
                af[mt] = *(const bf16x8*)&bb[(e64 + mt * 16 + l15) * 64 + sl];
            #pragma unroll
            for (int nt = 0; nt < 2; ++nt)
                bfr[nt] = *(const bf16x8*)&bb[16384 + (h * 32 + nt * 16 + l15) * 64 + sl];
            #pragma unroll
            for (int mt = 0; mt < 4; ++mt)
                #pragma unroll
                for (int nt = 0; nt < 2; ++nt)
                    acc[mt][nt] = __builtin_amdgcn_mfma_f32_16x16x32_bf16(af[mt], bfr[nt], acc[mt][nt], 0, 0, 0);
            if (gw4) {   // gate logits: rows 0-3 = experts, col b = wave*16+l15
                bf16x8 bfrg = *(const bf16x8*)&bb[16384 + (wave * 16 + l15) * 64 + sl];
                bf16x8 afg  = *(const bf16x8*)&u.s.gw[((t * 8 + ks * 4 + quad) * 4 + (l15 & 3)) * 8];
                accg = __builtin_amdgcn_mfma_f32_16x16x32_bf16(afg, bfrg, accg, 0, 0, 0);
            }
        }
        cur = (cur == 2) ? 0 : cur + 1;
    }
    __builtin_amdgcn_s_barrier();               // all buf reads done before Tt alias writes
    __builtin_amdgcn_sched_barrier(0);

    // tanh -> Tt_e[b][r] bf16 (wave writes its own (e,h) region)
    #pragma unroll
    for (int mt = 0; mt < 4; ++mt)
        #pragma unroll
        for (int nt = 0; nt < 2; ++nt) {
            int b = h * 32 + nt * 16 + l15;
            us o[4];
            #pragma unroll
            for (int i = 0; i < 4; ++i) o[i] = f2b(fast_tanh(acc[mt][nt][i]));
            *(ushort4*)&u.Tt[e][b * LDM + mt * 16 + quad * 4] = *(ushort4*)o;
        }
    if (gw4 && quad == 0) {   // accg rows 0-3 = logits e0..e3 for b = wave*16+l15
        float l0 = accg[0], l1 = accg[1], l2 = accg[2], l3 = accg[3];
        float m = fmaxf(fmaxf(l0, l1), fmaxf(l2, l3));
        float g0 = __expf(l0 - m), g1 = __expf(l1 - m);
        float g2 = __expf(l2 - m), g3 = __expf(l3 - m);
        float inv = 1.f / (g0 + g1 + g2 + g3);
        int b = wave * 16 + l15;
        u.s.gates[0 * 64 + b] = g0 * inv; u.s.gates[1 * 64 + b] = g1 * inv;
        u.s.gates[2 * 64 + b] = g2 * inv; u.s.gates[3 * 64 + b] = g3 * inv;
    }
    __syncthreads();

    // t2 = tanh(C_e @ t1); C-frags from packed Cp (coalesced: base + lane*16B)
    f32x4 acc2[4][2] = {};
    #pragma unroll
    for (int ks = 0; ks < 2; ++ks) {
        bf16x8 af2[4], bf2[2];
        #pragma unroll
        for (int mt = 0; mt < 4; ++mt)
            af2[mt] = *(const bf16x8*)&Cp[(size_t)(((e * 2 + ks) * 4 + mt) * 64 + lane) * 8];
        #pragma unroll
        for (int nt = 0; nt < 2; ++nt)
            bf2[nt] = *(const bf16x8*)&u.Tt[e][(h * 32 + nt * 16 + l15) * LDM + ks * 32 + quad * 8];
        #pragma unroll
        for (int mt = 0; mt < 4; ++mt)
            #pragma unroll
            for (int nt = 0; nt < 2; ++nt)
                acc2[mt][nt] = __builtin_amdgcn_mfma_f32_16x16x32_bf16(af2[mt], bf2[nt], acc2[mt][nt], 0, 0, 0);
    }
    __syncthreads();               // ALL Tt reads done before wlds (aliases Tt) writes

    // w = g * tanh(acc2) -> wlds[b][col] with 16B-chunk XOR swizzle: cc' = cc ^ (b&7)
    #pragma unroll
    for (int mt = 0; mt < 4; ++mt)
        #pragma unroll
        for (int nt = 0; nt < 2; ++nt) {
            int b = h * 32 + nt * 16 + l15;
            float g = u.s.gates[e64 + b];
            us o[4];
            #pragma unroll
            for (int i = 0; i < 4; ++i) o[i] = f2b(g * fast_tanh(acc2[mt][nt][i]));
            int col = e64 + mt * 16 + quad * 4;
            int cc = col >> 3, off = col & 7;
            *(ushort4*)&u.p2.wlds[b * 256 + ((cc ^ (b & 7)) << 3) + off] = *(ushort4*)o;
        }
    __syncthreads();               // wlds ready; phase 2 is barrier-free

    // ---- phase 2: D[d][b] = U . w^T; wave owns 64 d per pass, all 64 b ----
    const int bl = lane >> 2, dc3 = lane & 3;
    #pragma unroll 1
    for (int p = 0; p < 2; ++p) {
        const int dw = p * 512 + wave * 64;
        f32x4 pac[4][4] = {};
        bf16x8 a0[4], a1[4];
        #define LOADU(dst, S) { const int base = (S) * 64 + p * 32 + wave * 4;             \
            _Pragma("unroll")                                                              \
            for (int mt = 0; mt < 4; ++mt)                                                 \
                dst[mt] = *(const bf16x8*)&Up[(size_t)((base + mt) * 64 + lane) * 8]; }
        #define LOADW(dst, S) { const int e2 = (S) >> 1, r0q = ((S) & 1) * 32;            \
            _Pragma("unroll")                                                              \
            for (int nt = 0; nt < 4; ++nt) {                                               \
                int b = nt * 16 + l15;                                                     \
                int cc = e2 * 8 + (r0q >> 3) + quad;                                       \
                dst[nt] = *(const bf16x8*)&u.p2.wlds[b * 256 + ((cc ^ (b & 7)) << 3)];     \
            } }
        #define MM(A, W) { _Pragma("unroll")                                               \
            for (int mt = 0; mt < 4; ++mt) { _Pragma("unroll")                             \
                for (int nt = 0; nt < 4; ++nt)                                             \
                    pac[mt][nt] = __builtin_amdgcn_mfma_f32_16x16x32_bf16(A[mt], W[nt], pac[mt][nt], 0, 0, 0); } }
        LOADU(a0, 0);
        #pragma unroll
        for (int sp = 0; sp < 4; ++sp) {
            bf16x8 w0[4], w1[4];
            LOADU(a1, 2 * sp + 1);
            LOADW(w0, 2 * sp);
            MM(a0, w0);
            if (sp < 3) LOADU(a0, 2 * sp + 2);
            LOADW(w1, 2 * sp + 1);
            MM(a1, w1);
        }
        #undef LOADU
        #undef LOADW
        #undef MM

        // epilogue: hoist ALL x0/xs loads for this pass (4 nt), then bias, transpose, store
        const int dg = dw + dc3 * 16;
        uint4 X[4][2], L[4][2];
        #pragma unroll
        for (int nt = 0; nt < 4; ++nt) {
            const size_t gb = (size_t)(row0 + nt * 16 + bl) * DD + dg;
            X[nt][0] = *(const uint4*)&x0b[gb];     X[nt][1] = *(const uint4*)&x0b[gb + 8];
            L[nt][0] = *(const uint4*)&xs[gb];      L[nt][1] = *(const uint4*)&xs[gb + 8];
        }
        float bfv[16];
        *(float4*)&bfv[0]  = *(const float4*)&biasl[dg];
        *(float4*)&bfv[4]  = *(const float4*)&biasl[dg + 4];
        *(float4*)&bfv[8]  = *(const float4*)&biasl[dg + 8];
        *(float4*)&bfv[12] = *(const float4*)&biasl[dg + 12];
        float* sw = u.p2.smf[wave];   // wave-private 4 KB; per-wave DS ops are in-order
        #pragma unroll
        for (int nt = 0; nt < 4; ++nt) {
            #pragma unroll
            for (int mt = 0; mt < 4; ++mt) {
                int ch = (mt * 4 + quad) ^ (l15 & 7);
                *(f32x4*)&sw[l15 * 64 + ch * 4] = pac[mt][nt];
            }
            asm volatile("s_waitcnt lgkmcnt(0)" ::: "memory");
            __builtin_amdgcn_sched_barrier(0);
            const size_t gb = (size_t)(row0 + nt * 16 + bl) * DD + dg;
            uint xu[8], lu[8];
            *(uint4*)&xu[0] = X[nt][0]; *(uint4*)&xu[4] = X[nt][1];
            *(uint4*)&lu[0] = L[nt][0]; *(uint4*)&lu[4] = L[nt][1];
            float o[16];
            #pragma unroll
            for (int j = 0; j < 4; ++j) {
                int ch = (dc3 * 4 + j) ^ (bl & 7);
                float4 a = *(const float4*)&sw[bl * 64 + ch * 4];
                #pragma unroll
                for (int i = 0; i < 4; ++i) {
                    int k = j * 4 + i;
                    float av = (i == 0) ? a.x : (i == 1) ? a.y : (i == 2) ? a.z : a.w;
                    uint uu = xu[k >> 1], ll = lu[k >> 1];
                    float xv = b2f((k & 1) ? (us)(uu >> 16) : (us)(uu & 0xffff));
                    float xl = b2f((k & 1) ? (us)(ll >> 16) : (us)(ll & 0xffff));
                    o[k] = xv * (av + bfv[k]) + xl;
                }
            }
            if (last) {
                *(float4*)&out[gb]      = *(float4*)&o[0];
                *(float4*)&out[gb + 4]  = *(float4*)&o[4];
                *(float4*)&out[gb + 8]  = *(float4*)&o[8];
                *(float4*)&out[gb + 12] = *(float4*)&o[12];
            } else {
                us ob[16];
                #pragma unroll
                for (int k = 0; k < 16; ++k) ob[k] = f2b(o[k]);
                *(uint4*)&xbo[gb]     = *(uint4*)&ob[0];
                *(uint4*)&xbo[gb + 8] = *(uint4*)&ob[8];
            }
        }
    }
}

extern "C" void kernel_launch(void* const* d_in, const int* in_sizes, int n_in,
                              void* d_out, int out_size, void* d_ws, size_t ws_size,
                              hipStream_t stream) {
    const float* inputs = (const float*)d_in[0];
    const float* U      = (const float*)d_in[1];
    const float* V      = (const float*)d_in[2];
    const float* C      = (const float*)d_in[3];
    const float* gw     = (const float*)d_in[4];
    const float* bias   = (const float*)d_in[5];
    float* out = (float*)d_out;

    // ws: xb0 33.55 | xb 33.55 | gwb 8KB | Vp 1.57 | Up 1.57 | Cp 0.10  = ~70.3 MB
    us* xb0 = (us*)d_ws;                         // bf16(inputs), const across layers
    us* xb  = xb0 + (size_t)BB * DD;             // residual stream
    us* gwb = xb + (size_t)BB * DD;
    us* Vp  = gwb + (size_t)EE * DD;
    us* Up  = Vp + (size_t)LL * EE * RR * DD;
    us* Cp  = Up + (size_t)LL * EE * DD * RR;

    convF2B<<<dim3(BB * DD / 1024), 256, 0, stream>>>(inputs, xb0);
    convU<<<dim3(LL * EE * DD * RR / 8 / 256), 256, 0, stream>>>(U, Up);
    convC<<<dim3(LL * EE * RR * RR / 8 / 256), 256, 0, stream>>>(C, Cp);
    convF2B<<<dim3(EE * DD / 1024), 256, 0, stream>>>(gw, gwb);
    convV<<<dim3(LL * EE, DD / 64), 256, 0, stream>>>(V, Vp);

    for (int i = 0; i < LL; ++i) {
        const us* xs = (i == 0) ? xb0 : xb;
        layer_fused<<<dim3(BB / 64), 512, 0, stream>>>(
            xs, Vp + (size_t)i * EE * RR * DD, Cp + (size_t)i * EE * RR * RR, gwb,
            xb0, Up + (size_t)i * EE * DD * RR, xb, bias + (size_t)i * DD,
            out, i == LL - 1);
    }
}